// Round 9
// baseline (161.730 us; speedup 1.0000x reference)
//
#include <hip/hip_runtime.h>
#include <math.h>

// Problem constants (fixed by the reference setup_inputs)
#define NIMG   64
#define CDIM   64
#define HWPX   4096
#define KCL    128
#define TL     32                // pixels per chunk
#define NCH_IMG 128              // chunks per image (HWPX/TL)
#define SHIFT  10.0f             // softmax shift folded into bias
#define RSQRT128 0.08838834764831845f

// LDS strides in shorts (multiples of 8 so b128 stays 16B-aligned)
#define XP_S 72    // xp planes [32 p][64 c]
#define XC_S 40    // xc planes [64 c][32 p]
#define PH_S 40    // ph planes [128 k][32 p]

typedef __attribute__((ext_vector_type(8))) short short8; // 8 bf16
typedef __attribute__((ext_vector_type(4))) float f32x4;  // MFMA C/D

#define MFMA(a, b, c) __builtin_amdgcn_mfma_f32_16x16x32_bf16((a), (b), (c), 0, 0, 0)

// truncation split: hi = top16 bits, lo = bf16(f - hi). Dropped lo*lo term
// ~2^-16 relative -- well inside the 4.3e-4 output threshold.
__device__ __forceinline__ void tsplit(float f, short& hs, short& ls) {
    unsigned u = __builtin_bit_cast(unsigned, f);
    hs = (short)(u >> 16);
    float hf = __builtin_bit_cast(float, u & 0xffff0000u);
    ls = (short)(__builtin_bit_cast(unsigned, f - hf) >> 16);
}

// ---------------------------------------------------------------------------
// Kernel 1: raw-x planes -> mm1 (W@X) -> in-register softmax -> mm2 (P'@X^T)
// grid = NIMG*nparts blocks of 256 threads; block (n,part) covers chunks
// [part*128/nparts, (part+1)*128/nparts). nparts<=12 keeps every block
// resident (768 = 3 blocks/CU, LDS 3x41.5KB, regs 152<=170). Round-7-proven
// body: 3 barriers/chunk; NO device-scope fences (round-6: 3x cost).
// ---------------------------------------------------------------------------
__global__ __launch_bounds__(256, 3)
void netvlad_main(const float* __restrict__ x,       // [N][C][HW]
                  const float* __restrict__ conv_w,  // [K][C]
                  const float* __restrict__ conv_b,  // [K]
                  float* __restrict__ vout,          // partials or atomic acc
                  float* __restrict__ asout,
                  int nparts,
                  int use_atomic)
{
    __shared__ __align__(16) short xp_hi[TL * XP_S],  xp_lo[TL * XP_S];   // 9 KB
    __shared__ __align__(16) short xc_hi[CDIM * XC_S], xc_lo[CDIM * XC_S];// 10 KB
    __shared__ __align__(16) short ph_hi[KCL * PH_S],  ph_lo[KCL * PH_S]; // 20 KB
    __shared__ float redA[4 * 33];    // ssq partials [wave][p], stride 33
    __shared__ float sumP[4 * TL];    // exp-sum partials [wave][p]

    const int t   = threadIdx.x;
    const int w   = t >> 6;             // wave 0..3
    const int l   = t & 63;
    const int l15 = l & 15, l4 = l >> 4;
    const int n    = blockIdx.x / nparts;
    const int part = blockIdx.x - n * nparts;
    const int ch0  = (part * NCH_IMG) / nparts;        // first chunk
    const int ch1  = ((part + 1) * NCH_IMG) / nparts;  // one past last
    const int p_s  = t & 31;            // staging pixel
    const int sg   = t >> 5;            // staging c-group (8 c's)

    // ---- W fragments in registers (once): A[m=k][kdim=c] ------------------
    short8 wh[2][2], wl[2][2];
    #pragma unroll
    for (int kt = 0; kt < 2; ++kt) {
        const int krow = (2 * w + kt) * 16 + l15;
        #pragma unroll
        for (int ks = 0; ks < 2; ++ks) {
            const float4* wp = (const float4*)(conv_w + krow * CDIM + ks * 32 + l4 * 8);
            float4 wa = wp[0], wb = wp[1];
            float wv[8] = {wa.x, wa.y, wa.z, wa.w, wb.x, wb.y, wb.z, wb.w};
            #pragma unroll
            for (int j = 0; j < 8; ++j) {
                short hs, ls; tsplit(wv[j], hs, ls);
                wh[kt][ks][j] = hs; wl[kt][ks][j] = ls;
            }
        }
    }
    // bias per D-row (k = (2w+kt)*16 + l4*4 + i), pre-shifted
    float cbr[2][4];
    #pragma unroll
    for (int kt = 0; kt < 2; ++kt)
        #pragma unroll
        for (int i = 0; i < 4; ++i)
            cbr[kt][i] = conv_b[(2 * w + kt) * 16 + l4 * 4 + i] - SHIFT;

    f32x4 acc2[2][4];                   // V tiles [kt][ct]
    #pragma unroll
    for (int a = 0; a < 2; ++a)
        #pragma unroll
        for (int b = 0; b < 4; ++b) acc2[a][b] = (f32x4)0.0f;
    float asr[2][4];                    // asum partials per D-row
    #pragma unroll
    for (int a = 0; a < 2; ++a)
        #pragma unroll
        for (int i = 0; i < 4; ++i) asr[a][i] = 0.f;

    const float* xbase = x + (size_t)n * CDIM * HWPX;

    // preload first chunk
    float xv[8];
    #pragma unroll
    for (int j = 0; j < 8; ++j)
        xv[j] = xbase[(sg * 8 + j) * HWPX + ch0 * TL + p_s];

    for (int ch = ch0; ch < ch1; ++ch) {
        // ---- stage: ssq partial + raw-x split planes ----------------------
        float ssq = 0.f;
        #pragma unroll
        for (int j = 0; j < 8; ++j) ssq += xv[j] * xv[j];
        ssq += __shfl_xor(ssq, 32);              // combine the wave's 2 sg's
        if (l < 32) redA[w * 33 + p_s] = ssq;

        short8 vh, vl;
        #pragma unroll
        for (int j = 0; j < 8; ++j) {
            short hs, ls; tsplit(xv[j], hs, ls);
            vh[j] = hs; vl[j] = ls;
            xc_hi[(sg * 8 + j) * XC_S + p_s] = hs;
            xc_lo[(sg * 8 + j) * XC_S + p_s] = ls;
        }
        *(short8*)&xp_hi[p_s * XP_S + sg * 8] = vh;
        *(short8*)&xp_lo[p_s * XP_S + sg * 8] = vl;
        __syncthreads();                                  // bar 1: stage done

        // prefetch next chunk while mm1/softmax/mm2 run
        if (ch + 1 < ch1) {
            #pragma unroll
            for (int j = 0; j < 8; ++j)
                xv[j] = xbase[(sg * 8 + j) * HWPX + (ch + 1) * TL + p_s];
        }

        // ---- mm1: a1[kt][pt] = W @ Xraw  (D rows=k, cols=p) --------------
        f32x4 a1[2][2];
        #pragma unroll
        for (int a = 0; a < 2; ++a)
            #pragma unroll
            for (int b = 0; b < 2; ++b) a1[a][b] = (f32x4)0.0f;
        #pragma unroll
        for (int ks = 0; ks < 2; ++ks) {
            #pragma unroll
            for (int pt = 0; pt < 2; ++pt) {
                short8 bh = *(short8*)&xp_hi[(pt * 16 + l15) * XP_S + ks * 32 + l4 * 8];
                short8 bl = *(short8*)&xp_lo[(pt * 16 + l15) * XP_S + ks * 32 + l4 * 8];
                #pragma unroll
                for (int kt = 0; kt < 2; ++kt) {
                    a1[kt][pt] = MFMA(wh[kt][ks], bh, a1[kt][pt]);
                    a1[kt][pt] = MFMA(wh[kt][ks], bl, a1[kt][pt]);
                    a1[kt][pt] = MFMA(wl[kt][ks], bh, a1[kt][pt]);
                }
            }
        }

        // ---- per-column 1/||x||: sum the 4 per-wave ssq partials ----------
        float rn[2];
        #pragma unroll
        for (int pt = 0; pt < 2; ++pt) {
            const int col = pt * 16 + l15;
            float s0 = redA[col] + redA[33 + col];
            float s1 = redA[2 * 33 + col] + redA[3 * 33 + col];
            rn[pt] = 1.0f / fmaxf(sqrtf(s0 + s1), 1e-12f);
        }

        // ---- in-register softmax over k (no max pass; bias pre-shifted) ---
        float e[2][2][4], sp[2] = {0.f, 0.f};
        #pragma unroll
        for (int kt = 0; kt < 2; ++kt)
            #pragma unroll
            for (int pt = 0; pt < 2; ++pt)
                #pragma unroll
                for (int i = 0; i < 4; ++i) {
                    float ev = __expf(fmaf(a1[kt][pt][i], rn[pt], cbr[kt][i]));
                    e[kt][pt][i] = ev;
                    sp[pt] += ev;
                }
        #pragma unroll
        for (int pt = 0; pt < 2; ++pt) {
            sp[pt] += __shfl_xor(sp[pt], 16);
            sp[pt] += __shfl_xor(sp[pt], 32);     // wave-sum over its 32 k's
        }
        if (l4 == 0) {
            sumP[w * TL + l15]      = sp[0];
            sumP[w * TL + 16 + l15] = sp[1];
        }
        __syncthreads();                                  // bar 2: sumP done

        float rden[2], rdn2[2];
        #pragma unroll
        for (int pt = 0; pt < 2; ++pt) {
            const int col = pt * 16 + l15;
            float den = sumP[col] + sumP[TL + col] + sumP[2 * TL + col] + sumP[3 * TL + col];
            rden[pt] = 1.0f / den;
            rdn2[pt] = rden[pt] * rn[pt];          // fold 1/||x|| into P'
        }

        // ---- P' = P * rn, split to planes (wave's own 32 ph rows) ---------
        #pragma unroll
        for (int kt = 0; kt < 2; ++kt)
            #pragma unroll
            for (int i = 0; i < 4; ++i) {
                const int row = (2 * w + kt) * 16 + l4 * 4 + i;
                #pragma unroll
                for (int pt = 0; pt < 2; ++pt) {
                    float ev = e[kt][pt][i];
                    asr[kt][i] = fmaf(ev, rden[pt], asr[kt][i]);
                    float Pn = ev * rdn2[pt];
                    short hs, ls; tsplit(Pn, hs, ls);
                    ph_hi[row * PH_S + pt * 16 + l15] = hs;
                    ph_lo[row * PH_S + pt * 16 + l15] = ls;
                }
            }
        // no barrier: mm2 reads only the ph rows this wave just wrote
        // (intra-wave LDS ordering is guaranteed).

        // ---- mm2: V[k][c] += P' @ Xraw^T ---------------------------------
        {
            short8 xh2[4], xl2[4];
            #pragma unroll
            for (int ct = 0; ct < 4; ++ct) {
                xh2[ct] = *(short8*)&xc_hi[(ct * 16 + l15) * XC_S + l4 * 8];
                xl2[ct] = *(short8*)&xc_lo[(ct * 16 + l15) * XC_S + l4 * 8];
            }
            #pragma unroll
            for (int kt = 0; kt < 2; ++kt) {
                short8 ah = *(short8*)&ph_hi[((2 * w + kt) * 16 + l15) * PH_S + l4 * 8];
                short8 al = *(short8*)&ph_lo[((2 * w + kt) * 16 + l15) * PH_S + l4 * 8];
                #pragma unroll
                for (int ct = 0; ct < 4; ++ct) {
                    acc2[kt][ct] = MFMA(ah, xh2[ct], acc2[kt][ct]);
                    acc2[kt][ct] = MFMA(ah, xl2[ct], acc2[kt][ct]);
                    acc2[kt][ct] = MFMA(al, xh2[ct], acc2[kt][ct]);
                }
            }
        }
        __syncthreads();                                  // bar 3: chunk end
    }

    // ---- V write (coalesced: lanes l15 -> consecutive c) ------------------
    float* vg = use_atomic ? vout + (size_t)n * KCL * CDIM
                           : vout + (size_t)blockIdx.x * KCL * CDIM;
    #pragma unroll
    for (int kt = 0; kt < 2; ++kt)
        #pragma unroll
        for (int ct = 0; ct < 4; ++ct)
            #pragma unroll
            for (int i = 0; i < 4; ++i) {
                const int row = (2 * w + kt) * 16 + l4 * 4 + i;
                const int col = ct * 16 + l15;
                if (use_atomic) atomicAdd(&vg[row * CDIM + col], acc2[kt][ct][i]);
                else            vg[row * CDIM + col] = acc2[kt][ct][i];
            }

    // ---- asum: reduce over l15 lanes, lane0-of-16 writes ------------------
    #pragma unroll
    for (int kt = 0; kt < 2; ++kt)
        #pragma unroll
        for (int i = 0; i < 4; ++i) {
            float v = asr[kt][i];
            v += __shfl_xor(v, 1); v += __shfl_xor(v, 2);
            v += __shfl_xor(v, 4); v += __shfl_xor(v, 8);
            if (l15 == 0) {
                const int row = (2 * w + kt) * 16 + l4 * 4 + i;
                if (use_atomic) atomicAdd(&asout[n * KCL + row], v);
                else            asout[blockIdx.x * KCL + row] = v;
            }
        }
}

// ---------------------------------------------------------------------------
// Kernel 2: sum partials; vlad = V - asum*cent; intra-norm; global norm.
// After intra-norm every row has unit L2 norm -> global denom = sqrt(128).
// grid = NIMG*8 blocks x 256 threads; thread -> (k, 4 c's). Fully parallel.
// ---------------------------------------------------------------------------
__global__ __launch_bounds__(256)
void netvlad_finalize(const float* __restrict__ vpart,   // [N][nparts][K][C]
                      const float* __restrict__ aspart,  // [N][nparts][K]
                      const float* __restrict__ cent,    // [K][C]
                      float* __restrict__ out,           // [N][K*C]
                      int nparts)
{
    const int t = threadIdx.x;
    const int n  = blockIdx.x >> 3;
    const int kg = blockIdx.x & 7;
    const int k  = kg * 16 + (t >> 4);
    const int c0 = (t & 15) * 4;

    float vsum[4] = {0.f, 0.f, 0.f, 0.f};
    float av = 0.f;
    for (int pt = 0; pt < nparts; ++pt) {
        const float* vg = vpart + (((size_t)n * nparts + pt) * KCL + k) * CDIM + c0;
        float4 a = *(const float4*)vg;
        vsum[0] += a.x; vsum[1] += a.y; vsum[2] += a.z; vsum[3] += a.w;
        av += aspart[(n * nparts + pt) * KCL + k];
    }

    float4 cq = *(const float4*)(cent + k * CDIM + c0);
    float cc[4] = {cq.x, cq.y, cq.z, cq.w};
    float ss = 0.f;
    #pragma unroll
    for (int j = 0; j < 4; ++j) {
        vsum[j] -= av * cc[j];
        ss += vsum[j] * vsum[j];
    }
    // row sumsq over the 16 lanes covering this k
    ss += __shfl_xor(ss, 1); ss += __shfl_xor(ss, 2);
    ss += __shfl_xor(ss, 4); ss += __shfl_xor(ss, 8);
    const float s = (1.0f / fmaxf(sqrtf(ss), 1e-12f)) * RSQRT128;

    float4 o;
    o.x = vsum[0] * s; o.y = vsum[1] * s; o.z = vsum[2] * s; o.w = vsum[3] * s;
    *(float4*)(out + (size_t)n * KCL * CDIM + k * CDIM + c0) = o;
}

// ---------------------------------------------------------------------------
extern "C" void kernel_launch(void* const* d_in, const int* in_sizes, int n_in,
                              void* d_out, int out_size, void* d_ws, size_t ws_size,
                              hipStream_t stream) {
    const float* x     = (const float*)d_in[0];   // [64,64,64,64]
    const float* cent  = (const float*)d_in[1];   // [128,64]
    const float* convw = (const float*)d_in[2];   // [128,64]
    const float* convb = (const float*)d_in[3];   // [128]
    float* out = (float*)d_out;

    // Pick the largest nparts (<=12 so every block is co-resident at
    // 3 blocks/CU) whose fp32 partials fit the workspace. 8 is the
    // proven-to-fit floor; below that, atomic fallback.
    int nparts = 0;
    for (int p = 12; p >= 8; --p) {
        size_t need = (size_t)NIMG * p * (KCL * CDIM + KCL) * sizeof(float);
        if (ws_size >= need) { nparts = p; break; }
    }

    if (nparts > 0) {
        float* vws  = (float*)d_ws;                               // [N][np][K][C]
        float* asws = vws + (size_t)NIMG * nparts * KCL * CDIM;   // [N][np][K]
        netvlad_main<<<dim3(NIMG * nparts), dim3(256), 0, stream>>>(
            x, convw, convb, vws, asws, nparts, 0);
        netvlad_finalize<<<dim3(NIMG * 8), dim3(256), 0, stream>>>(
            vws, asws, cent, out, nparts);
    } else {
        float* vws  = (float*)d_ws;                               // [N][K][C]
        float* asws = vws + (size_t)NIMG * KCL * CDIM;            // [N][K]
        const size_t zb = (size_t)NIMG * (KCL * CDIM + KCL) * sizeof(float);
        hipMemsetAsync(d_ws, 0, zb, stream);
        netvlad_main<<<dim3(NIMG * 8), dim3(256), 0, stream>>>(
            x, convw, convb, vws, asws, 8, 1);
        netvlad_finalize<<<dim3(NIMG * 8), dim3(256), 0, stream>>>(
            vws, asws, cent, out, 1);
    }
}

// Round 10
// 143.300 us; speedup vs baseline: 1.1286x; 1.1286x over previous
//
#include <hip/hip_runtime.h>
#include <math.h>

// Problem constants (fixed by the reference setup_inputs)
#define NIMG   64
#define CDIM   64
#define HWPX   4096
#define KCL    128
#define TL     32                // pixels per chunk
#define NCH_IMG 128              // chunks per image (HWPX/TL)
#define SHIFT  10.0f             // softmax shift folded into bias
#define RSQRT128 0.08838834764831845f

// LDS strides in shorts (multiples of 8 so b128 stays 16B-aligned)
#define XP_S 72    // xp planes [32 p][64 c]
#define XC_S 40    // xc planes [64 c][32 p]
#define PH_S 40    // ph planes [128 k][32 p]

typedef __attribute__((ext_vector_type(8))) short short8; // 8 bf16
typedef __attribute__((ext_vector_type(4))) float f32x4;  // MFMA C/D

#define MFMA(a, b, c) __builtin_amdgcn_mfma_f32_16x16x32_bf16((a), (b), (c), 0, 0, 0)

// truncation split: hi = top16 bits, lo = bf16(f - hi). Dropped lo*lo term
// ~2^-16 relative -- well inside the 4.3e-4 output threshold.
__device__ __forceinline__ void tsplit(float f, short& hs, short& ls) {
    unsigned u = __builtin_bit_cast(unsigned, f);
    hs = (short)(u >> 16);
    float hf = __builtin_bit_cast(float, u & 0xffff0000u);
    ls = (short)(__builtin_bit_cast(unsigned, f - hf) >> 16);
}

// ---------------------------------------------------------------------------
// Kernel 1: raw-x planes -> mm1 (W@X) -> in-register softmax -> mm2 (P'@X^T)
// Round-7-proven body: 41.5 KB LDS, 3 barriers/chunk, launch_bounds(256,2).
// LESSONS (measured): (256,3) => VGPR capped at 84 + scratch spill (r3, r9);
// __threadfence in-kernel => 3x slowdown (r6); 512-thr blocks => conflicts
// (r5). Grid = NIMG*NP blocks; NP=12 -> 768 blocks = 3 blocks/CU resident
// (LDS 3x41.5=124.5 <= 160 KB, VGPR 120 <= 170). Uneven chunk split via
// compile-time NP (constant-divisor magic-mul, no allocator perturbation).
// ---------------------------------------------------------------------------
template <int NP>
__global__ __launch_bounds__(256, 2)
void netvlad_main(const float* __restrict__ x,       // [N][C][HW]
                  const float* __restrict__ conv_w,  // [K][C]
                  const float* __restrict__ conv_b,  // [K]
                  float* __restrict__ vout,          // partials or atomic acc
                  float* __restrict__ asout,
                  int use_atomic)
{
    __shared__ __align__(16) short xp_hi[TL * XP_S],  xp_lo[TL * XP_S];   // 9 KB
    __shared__ __align__(16) short xc_hi[CDIM * XC_S], xc_lo[CDIM * XC_S];// 10 KB
    __shared__ __align__(16) short ph_hi[KCL * PH_S],  ph_lo[KCL * PH_S]; // 20 KB
    __shared__ float redA[4 * 33];    // ssq partials [wave][p], stride 33
    __shared__ float sumP[4 * TL];    // exp-sum partials [wave][p]

    const int t   = threadIdx.x;
    const int w   = t >> 6;             // wave 0..3
    const int l   = t & 63;
    const int l15 = l & 15, l4 = l >> 4;
    const int n    = blockIdx.x / NP;   // compile-time divisor
    const int part = blockIdx.x - n * NP;
    const int ch0  = (part * NCH_IMG) / NP;
    const int ch1  = ((part + 1) * NCH_IMG) / NP;
    const int p_s  = t & 31;            // staging pixel
    const int sg   = t >> 5;            // staging c-group (8 c's)

    // ---- W fragments in registers (once): A[m=k][kdim=c] ------------------
    short8 wh[2][2], wl[2][2];
    #pragma unroll
    for (int kt = 0; kt < 2; ++kt) {
        const int krow = (2 * w + kt) * 16 + l15;
        #pragma unroll
        for (int ks = 0; ks < 2; ++ks) {
            const float4* wp = (const float4*)(conv_w + krow * CDIM + ks * 32 + l4 * 8);
            float4 wa = wp[0], wb = wp[1];
            float wv[8] = {wa.x, wa.y, wa.z, wa.w, wb.x, wb.y, wb.z, wb.w};
            #pragma unroll
            for (int j = 0; j < 8; ++j) {
                short hs, ls; tsplit(wv[j], hs, ls);
                wh[kt][ks][j] = hs; wl[kt][ks][j] = ls;
            }
        }
    }
    // bias per D-row (k = (2w+kt)*16 + l4*4 + i), pre-shifted
    float cbr[2][4];
    #pragma unroll
    for (int kt = 0; kt < 2; ++kt)
        #pragma unroll
        for (int i = 0; i < 4; ++i)
            cbr[kt][i] = conv_b[(2 * w + kt) * 16 + l4 * 4 + i] - SHIFT;

    f32x4 acc2[2][4];                   // V tiles [kt][ct]
    #pragma unroll
    for (int a = 0; a < 2; ++a)
        #pragma unroll
        for (int b = 0; b < 4; ++b) acc2[a][b] = (f32x4)0.0f;
    float asr[2][4];                    // asum partials per D-row
    #pragma unroll
    for (int a = 0; a < 2; ++a)
        #pragma unroll
        for (int i = 0; i < 4; ++i) asr[a][i] = 0.f;

    const float* xbase = x + (size_t)n * CDIM * HWPX;

    // preload first chunk
    float xv[8];
    #pragma unroll
    for (int j = 0; j < 8; ++j)
        xv[j] = xbase[(sg * 8 + j) * HWPX + ch0 * TL + p_s];

    for (int ch = ch0; ch < ch1; ++ch) {
        // ---- stage: ssq partial + raw-x split planes ----------------------
        float ssq = 0.f;
        #pragma unroll
        for (int j = 0; j < 8; ++j) ssq += xv[j] * xv[j];
        ssq += __shfl_xor(ssq, 32);              // combine the wave's 2 sg's
        if (l < 32) redA[w * 33 + p_s] = ssq;

        short8 vh, vl;
        #pragma unroll
        for (int j = 0; j < 8; ++j) {
            short hs, ls; tsplit(xv[j], hs, ls);
            vh[j] = hs; vl[j] = ls;
            xc_hi[(sg * 8 + j) * XC_S + p_s] = hs;
            xc_lo[(sg * 8 + j) * XC_S + p_s] = ls;
        }
        *(short8*)&xp_hi[p_s * XP_S + sg * 8] = vh;
        *(short8*)&xp_lo[p_s * XP_S + sg * 8] = vl;
        __syncthreads();                                  // bar 1: stage done

        // prefetch next chunk while mm1/softmax/mm2 run
        if (ch + 1 < ch1) {
            #pragma unroll
            for (int j = 0; j < 8; ++j)
                xv[j] = xbase[(sg * 8 + j) * HWPX + (ch + 1) * TL + p_s];
        }

        // ---- mm1: a1[kt][pt] = W @ Xraw  (D rows=k, cols=p) --------------
        f32x4 a1[2][2];
        #pragma unroll
        for (int a = 0; a < 2; ++a)
            #pragma unroll
            for (int b = 0; b < 2; ++b) a1[a][b] = (f32x4)0.0f;
        #pragma unroll
        for (int ks = 0; ks < 2; ++ks) {
            #pragma unroll
            for (int pt = 0; pt < 2; ++pt) {
                short8 bh = *(short8*)&xp_hi[(pt * 16 + l15) * XP_S + ks * 32 + l4 * 8];
                short8 bl = *(short8*)&xp_lo[(pt * 16 + l15) * XP_S + ks * 32 + l4 * 8];
                #pragma unroll
                for (int kt = 0; kt < 2; ++kt) {
                    a1[kt][pt] = MFMA(wh[kt][ks], bh, a1[kt][pt]);
                    a1[kt][pt] = MFMA(wh[kt][ks], bl, a1[kt][pt]);
                    a1[kt][pt] = MFMA(wl[kt][ks], bh, a1[kt][pt]);
                }
            }
        }

        // ---- per-column 1/||x||: sum the 4 per-wave ssq partials ----------
        float rn[2];
        #pragma unroll
        for (int pt = 0; pt < 2; ++pt) {
            const int col = pt * 16 + l15;
            float s0 = redA[col] + redA[33 + col];
            float s1 = redA[2 * 33 + col] + redA[3 * 33 + col];
            rn[pt] = 1.0f / fmaxf(sqrtf(s0 + s1), 1e-12f);
        }

        // ---- in-register softmax over k (no max pass; bias pre-shifted) ---
        float e[2][2][4], sp[2] = {0.f, 0.f};
        #pragma unroll
        for (int kt = 0; kt < 2; ++kt)
            #pragma unroll
            for (int pt = 0; pt < 2; ++pt)
                #pragma unroll
                for (int i = 0; i < 4; ++i) {
                    float ev = __expf(fmaf(a1[kt][pt][i], rn[pt], cbr[kt][i]));
                    e[kt][pt][i] = ev;
                    sp[pt] += ev;
                }
        #pragma unroll
        for (int pt = 0; pt < 2; ++pt) {
            sp[pt] += __shfl_xor(sp[pt], 16);
            sp[pt] += __shfl_xor(sp[pt], 32);     // wave-sum over its 32 k's
        }
        if (l4 == 0) {
            sumP[w * TL + l15]      = sp[0];
            sumP[w * TL + 16 + l15] = sp[1];
        }
        __syncthreads();                                  // bar 2: sumP done

        float rden[2], rdn2[2];
        #pragma unroll
        for (int pt = 0; pt < 2; ++pt) {
            const int col = pt * 16 + l15;
            float den = sumP[col] + sumP[TL + col] + sumP[2 * TL + col] + sumP[3 * TL + col];
            rden[pt] = 1.0f / den;
            rdn2[pt] = rden[pt] * rn[pt];          // fold 1/||x|| into P'
        }

        // ---- P' = P * rn, split to planes (wave's own 32 ph rows) ---------
        #pragma unroll
        for (int kt = 0; kt < 2; ++kt)
            #pragma unroll
            for (int i = 0; i < 4; ++i) {
                const int row = (2 * w + kt) * 16 + l4 * 4 + i;
                #pragma unroll
                for (int pt = 0; pt < 2; ++pt) {
                    float ev = e[kt][pt][i];
                    asr[kt][i] = fmaf(ev, rden[pt], asr[kt][i]);
                    float Pn = ev * rdn2[pt];
                    short hs, ls; tsplit(Pn, hs, ls);
                    ph_hi[row * PH_S + pt * 16 + l15] = hs;
                    ph_lo[row * PH_S + pt * 16 + l15] = ls;
                }
            }
        // no barrier: mm2 reads only the ph rows this wave just wrote
        // (intra-wave LDS ordering is guaranteed).

        // ---- mm2: V[k][c] += P' @ Xraw^T ---------------------------------
        {
            short8 xh2[4], xl2[4];
            #pragma unroll
            for (int ct = 0; ct < 4; ++ct) {
                xh2[ct] = *(short8*)&xc_hi[(ct * 16 + l15) * XC_S + l4 * 8];
                xl2[ct] = *(short8*)&xc_lo[(ct * 16 + l15) * XC_S + l4 * 8];
            }
            #pragma unroll
            for (int kt = 0; kt < 2; ++kt) {
                short8 ah = *(short8*)&ph_hi[((2 * w + kt) * 16 + l15) * PH_S + l4 * 8];
                short8 al = *(short8*)&ph_lo[((2 * w + kt) * 16 + l15) * PH_S + l4 * 8];
                #pragma unroll
                for (int ct = 0; ct < 4; ++ct) {
                    acc2[kt][ct] = MFMA(ah, xh2[ct], acc2[kt][ct]);
                    acc2[kt][ct] = MFMA(ah, xl2[ct], acc2[kt][ct]);
                    acc2[kt][ct] = MFMA(al, xh2[ct], acc2[kt][ct]);
                }
            }
        }
        __syncthreads();                                  // bar 3: chunk end
    }

    // ---- V write (coalesced: lanes l15 -> consecutive c) ------------------
    float* vg = use_atomic ? vout + (size_t)n * KCL * CDIM
                           : vout + (size_t)blockIdx.x * KCL * CDIM;
    #pragma unroll
    for (int kt = 0; kt < 2; ++kt)
        #pragma unroll
        for (int ct = 0; ct < 4; ++ct)
            #pragma unroll
            for (int i = 0; i < 4; ++i) {
                const int row = (2 * w + kt) * 16 + l4 * 4 + i;
                const int col = ct * 16 + l15;
                if (use_atomic) atomicAdd(&vg[row * CDIM + col], acc2[kt][ct][i]);
                else            vg[row * CDIM + col] = acc2[kt][ct][i];
            }

    // ---- asum: reduce over l15 lanes, lane0-of-16 writes ------------------
    #pragma unroll
    for (int kt = 0; kt < 2; ++kt)
        #pragma unroll
        for (int i = 0; i < 4; ++i) {
            float v = asr[kt][i];
            v += __shfl_xor(v, 1); v += __shfl_xor(v, 2);
            v += __shfl_xor(v, 4); v += __shfl_xor(v, 8);
            if (l15 == 0) {
                const int row = (2 * w + kt) * 16 + l4 * 4 + i;
                if (use_atomic) atomicAdd(&asout[n * KCL + row], v);
                else            asout[blockIdx.x * KCL + row] = v;
            }
        }
}

// ---------------------------------------------------------------------------
// Kernel 2: sum partials; vlad = V - asum*cent; intra-norm; global norm.
// After intra-norm every row has unit L2 norm -> global denom = sqrt(128).
// grid = NIMG*8 blocks x 256 threads; thread -> (k, 4 c's). Fully parallel.
// ---------------------------------------------------------------------------
__global__ __launch_bounds__(256)
void netvlad_finalize(const float* __restrict__ vpart,   // [N][nparts][K][C]
                      const float* __restrict__ aspart,  // [N][nparts][K]
                      const float* __restrict__ cent,    // [K][C]
                      float* __restrict__ out,           // [N][K*C]
                      int nparts)
{
    const int t = threadIdx.x;
    const int n  = blockIdx.x >> 3;
    const int kg = blockIdx.x & 7;
    const int k  = kg * 16 + (t >> 4);
    const int c0 = (t & 15) * 4;

    float vsum[4] = {0.f, 0.f, 0.f, 0.f};
    float av = 0.f;
    for (int pt = 0; pt < nparts; ++pt) {
        const float* vg = vpart + (((size_t)n * nparts + pt) * KCL + k) * CDIM + c0;
        float4 a = *(const float4*)vg;
        vsum[0] += a.x; vsum[1] += a.y; vsum[2] += a.z; vsum[3] += a.w;
        av += aspart[(n * nparts + pt) * KCL + k];
    }

    float4 cq = *(const float4*)(cent + k * CDIM + c0);
    float cc[4] = {cq.x, cq.y, cq.z, cq.w};
    float ss = 0.f;
    #pragma unroll
    for (int j = 0; j < 4; ++j) {
        vsum[j] -= av * cc[j];
        ss += vsum[j] * vsum[j];
    }
    // row sumsq over the 16 lanes covering this k
    ss += __shfl_xor(ss, 1); ss += __shfl_xor(ss, 2);
    ss += __shfl_xor(ss, 4); ss += __shfl_xor(ss, 8);
    const float s = (1.0f / fmaxf(sqrtf(ss), 1e-12f)) * RSQRT128;

    float4 o;
    o.x = vsum[0] * s; o.y = vsum[1] * s; o.z = vsum[2] * s; o.w = vsum[3] * s;
    *(float4*)(out + (size_t)n * KCL * CDIM + k * CDIM + c0) = o;
}

// ---------------------------------------------------------------------------
extern "C" void kernel_launch(void* const* d_in, const int* in_sizes, int n_in,
                              void* d_out, int out_size, void* d_ws, size_t ws_size,
                              hipStream_t stream) {
    const float* x     = (const float*)d_in[0];   // [64,64,64,64]
    const float* cent  = (const float*)d_in[1];   // [128,64]
    const float* convw = (const float*)d_in[2];   // [128,64]
    const float* convb = (const float*)d_in[3];   // [128]
    float* out = (float*)d_out;

    const size_t need12 = (size_t)NIMG * 12 * (KCL * CDIM + KCL) * sizeof(float);
    const size_t need8  = (size_t)NIMG * 8  * (KCL * CDIM + KCL) * sizeof(float);

    if (ws_size >= need12) {                      // proven to fit (round 9)
        float* vws  = (float*)d_ws;                               // [N][12][K][C]
        float* asws = vws + (size_t)NIMG * 12 * KCL * CDIM;       // [N][12][K]
        netvlad_main<12><<<dim3(NIMG * 12), dim3(256), 0, stream>>>(
            x, convw, convb, vws, asws, 0);
        netvlad_finalize<<<dim3(NIMG * 8), dim3(256), 0, stream>>>(
            vws, asws, cent, out, 12);
    } else if (ws_size >= need8) {
        float* vws  = (float*)d_ws;                               // [N][8][K][C]
        float* asws = vws + (size_t)NIMG * 8 * KCL * CDIM;        // [N][8][K]
        netvlad_main<8><<<dim3(NIMG * 8), dim3(256), 0, stream>>>(
            x, convw, convb, vws, asws, 0);
        netvlad_finalize<<<dim3(NIMG * 8), dim3(256), 0, stream>>>(
            vws, asws, cent, out, 8);
    } else {
        float* vws  = (float*)d_ws;                               // [N][K][C]
        float* asws = vws + (size_t)NIMG * KCL * CDIM;            // [N][K]
        const size_t zb = (size_t)NIMG * (KCL * CDIM + KCL) * sizeof(float);
        hipMemsetAsync(d_ws, 0, zb, stream);
        netvlad_main<8><<<dim3(NIMG * 8), dim3(256), 0, stream>>>(
            x, convw, convb, vws, asws, 1);
        netvlad_finalize<<<dim3(NIMG * 8), dim3(256), 0, stream>>>(
            vws, asws, cent, out, 1);
    }
}

// Round 11
// 127.542 us; speedup vs baseline: 1.2681x; 1.1236x over previous
//
#include <hip/hip_runtime.h>
#include <math.h>

// Problem constants (fixed by the reference setup_inputs)
#define NIMG   64
#define CDIM   64
#define HWPX   4096
#define PARTS  8                 // 512 blocks = 2/CU balanced (768 -> tail, r10)
#define KCL    128
#define PIXPART (HWPX / PARTS)   // 512 pixels per block
#define TL     32                // pixels per chunk
#define NCHUNK (PIXPART / TL)    // 16
#define SHIFT  10.0f             // softmax shift folded into bias
#define RSQRT128 0.08838834764831845f

// LDS strides in shorts (multiples of 8 so b128 stays 16B-aligned)
#define XP_S 72    // xp planes [32 p][64 c]
#define XC_S 40    // xc plane  [64 c][32 p]
#define PH_S 40    // ph plane  [128 k][32 p]

typedef __attribute__((ext_vector_type(8))) short short8; // 8 bf16
typedef __attribute__((ext_vector_type(4))) float f32x4;  // MFMA C/D

#define MFMA(a, b, c) __builtin_amdgcn_mfma_f32_16x16x32_bf16((a), (b), (c), 0, 0, 0)

// truncation split for mm1 (hi exact-prefix + lo correction): 3-term MFMA
__device__ __forceinline__ void tsplit(float f, short& hs, short& ls) {
    unsigned u = __builtin_bit_cast(unsigned, f);
    hs = (short)(u >> 16);
    float hf = __builtin_bit_cast(float, u & 0xffff0000u);
    ls = (short)(__builtin_bit_cast(unsigned, f - hf) >> 16);
}
// round-to-nearest-even bf16 for mm2's single-plane operands
__device__ __forceinline__ short f2bf(float f) {
    unsigned u = __builtin_bit_cast(unsigned, f);
    return (short)((u + 0x7fffu + ((u >> 16) & 1u)) >> 16);
}

// ---------------------------------------------------------------------------
// Kernel 1: raw-x planes -> mm1 (W@X, 3-term split) -> in-register softmax
// -> mm2 (P'@X^T, single bf16 planes -- error bounded ~4e-6 on output
// because the VLAD residual is dominated by asum*centroid).
// LESSONS (measured): (256,3)/spill r3+r9; __threadfence 3x r6; 512-thr
// blocks r5; 768 blocks tail r10. 512 blocks x 256 thr, 25.6 KB LDS,
// 3 barriers/chunk, launch_bounds(256,2).
// ---------------------------------------------------------------------------
template <int NP>
__global__ __launch_bounds__(256, 2)
void netvlad_main(const float* __restrict__ x,       // [N][C][HW]
                  const float* __restrict__ conv_w,  // [K][C]
                  const float* __restrict__ conv_b,  // [K]
                  float* __restrict__ vout,          // partials or atomic acc
                  float* __restrict__ asout,
                  int use_atomic)
{
    __shared__ __align__(16) short xp_hi[TL * XP_S], xp_lo[TL * XP_S]; // 9 KB
    __shared__ __align__(16) short xc[CDIM * XC_S];                    // 5 KB
    __shared__ __align__(16) short ph[KCL * PH_S];                     // 10 KB
    __shared__ float redA[4 * 33];    // ssq partials [wave][p], stride 33
    __shared__ float sumP[4 * TL];    // exp-sum partials [wave][p]

    const int t   = threadIdx.x;
    const int w   = t >> 6;             // wave 0..3
    const int l   = t & 63;
    const int l15 = l & 15, l4 = l >> 4;
    const int n    = blockIdx.x / NP;
    const int part = blockIdx.x - n * NP;
    const int p_s  = t & 31;            // staging pixel
    const int sg   = t >> 5;            // staging c-group (8 c's)

    // ---- W fragments in registers (once): A[m=k][kdim=c], 3-term split ----
    short8 wh[2][2], wl[2][2];
    #pragma unroll
    for (int kt = 0; kt < 2; ++kt) {
        const int krow = (2 * w + kt) * 16 + l15;
        #pragma unroll
        for (int ks = 0; ks < 2; ++ks) {
            const float4* wp = (const float4*)(conv_w + krow * CDIM + ks * 32 + l4 * 8);
            float4 wa = wp[0], wb = wp[1];
            float wv[8] = {wa.x, wa.y, wa.z, wa.w, wb.x, wb.y, wb.z, wb.w};
            #pragma unroll
            for (int j = 0; j < 8; ++j) {
                short hs, ls; tsplit(wv[j], hs, ls);
                wh[kt][ks][j] = hs; wl[kt][ks][j] = ls;
            }
        }
    }
    // bias per D-row (k = (2w+kt)*16 + l4*4 + i), pre-shifted
    float cbr[2][4];
    #pragma unroll
    for (int kt = 0; kt < 2; ++kt)
        #pragma unroll
        for (int i = 0; i < 4; ++i)
            cbr[kt][i] = conv_b[(2 * w + kt) * 16 + l4 * 4 + i] - SHIFT;

    f32x4 acc2[2][4];                   // V tiles [kt][ct]
    #pragma unroll
    for (int a = 0; a < 2; ++a)
        #pragma unroll
        for (int b = 0; b < 4; ++b) acc2[a][b] = (f32x4)0.0f;
    float asr[2][4];                    // asum partials per D-row
    #pragma unroll
    for (int a = 0; a < 2; ++a)
        #pragma unroll
        for (int i = 0; i < 4; ++i) asr[a][i] = 0.f;

    const float* xbase = x + (size_t)n * CDIM * HWPX + part * PIXPART;

    // preload chunk 0
    float xv[8];
    #pragma unroll
    for (int j = 0; j < 8; ++j)
        xv[j] = xbase[(sg * 8 + j) * HWPX + p_s];

    for (int ch = 0; ch < NCHUNK; ++ch) {
        // ---- stage: ssq partial + x planes --------------------------------
        float ssq = 0.f;
        #pragma unroll
        for (int j = 0; j < 8; ++j) ssq += xv[j] * xv[j];
        ssq += __shfl_xor(ssq, 32);              // combine the wave's 2 sg's
        if (l < 32) redA[w * 33 + p_s] = ssq;

        short8 vh, vl;
        #pragma unroll
        for (int j = 0; j < 8; ++j) {
            short hs, ls; tsplit(xv[j], hs, ls);
            vh[j] = hs; vl[j] = ls;
            xc[(sg * 8 + j) * XC_S + p_s] = f2bf(xv[j]);   // mm2 plane (RNE)
        }
        *(short8*)&xp_hi[p_s * XP_S + sg * 8] = vh;
        *(short8*)&xp_lo[p_s * XP_S + sg * 8] = vl;
        __syncthreads();                                  // bar 1: stage done

        // prefetch next chunk while mm1/softmax/mm2 run
        if (ch + 1 < NCHUNK) {
            #pragma unroll
            for (int j = 0; j < 8; ++j)
                xv[j] = xbase[(sg * 8 + j) * HWPX + (ch + 1) * TL + p_s];
        }

        // ---- mm1: a1[kt][pt] = W @ Xraw  (3-term split) -------------------
        f32x4 a1[2][2];
        #pragma unroll
        for (int a = 0; a < 2; ++a)
            #pragma unroll
            for (int b = 0; b < 2; ++b) a1[a][b] = (f32x4)0.0f;
        #pragma unroll
        for (int ks = 0; ks < 2; ++ks) {
            #pragma unroll
            for (int pt = 0; pt < 2; ++pt) {
                short8 bh = *(short8*)&xp_hi[(pt * 16 + l15) * XP_S + ks * 32 + l4 * 8];
                short8 bl = *(short8*)&xp_lo[(pt * 16 + l15) * XP_S + ks * 32 + l4 * 8];
                #pragma unroll
                for (int kt = 0; kt < 2; ++kt) {
                    a1[kt][pt] = MFMA(wh[kt][ks], bh, a1[kt][pt]);
                    a1[kt][pt] = MFMA(wh[kt][ks], bl, a1[kt][pt]);
                    a1[kt][pt] = MFMA(wl[kt][ks], bh, a1[kt][pt]);
                }
            }
        }

        // ---- per-column 1/||x||: sum the 4 per-wave ssq partials ----------
        float rn[2];
        #pragma unroll
        for (int pt = 0; pt < 2; ++pt) {
            const int col = pt * 16 + l15;
            float s0 = redA[col] + redA[33 + col];
            float s1 = redA[2 * 33 + col] + redA[3 * 33 + col];
            rn[pt] = 1.0f / fmaxf(sqrtf(s0 + s1), 1e-12f);
        }

        // ---- in-register softmax over k (no max pass; bias pre-shifted) ---
        float e[2][2][4], sp[2] = {0.f, 0.f};
        #pragma unroll
        for (int kt = 0; kt < 2; ++kt)
            #pragma unroll
            for (int pt = 0; pt < 2; ++pt)
                #pragma unroll
                for (int i = 0; i < 4; ++i) {
                    float ev = __expf(fmaf(a1[kt][pt][i], rn[pt], cbr[kt][i]));
                    e[kt][pt][i] = ev;
                    sp[pt] += ev;
                }
        #pragma unroll
        for (int pt = 0; pt < 2; ++pt) {
            sp[pt] += __shfl_xor(sp[pt], 16);
            sp[pt] += __shfl_xor(sp[pt], 32);     // wave-sum over its 32 k's
        }
        if (l4 == 0) {
            sumP[w * TL + l15]      = sp[0];
            sumP[w * TL + 16 + l15] = sp[1];
        }
        __syncthreads();                                  // bar 2: sumP done

        float rden[2], rdn2[2];
        #pragma unroll
        for (int pt = 0; pt < 2; ++pt) {
            const int col = pt * 16 + l15;
            float den = sumP[col] + sumP[TL + col] + sumP[2 * TL + col] + sumP[3 * TL + col];
            rden[pt] = 1.0f / den;
            rdn2[pt] = rden[pt] * rn[pt];          // fold 1/||x|| into P'
        }

        // ---- P' = P * rn -> single bf16 plane (wave's own 32 ph rows) -----
        #pragma unroll
        for (int kt = 0; kt < 2; ++kt)
            #pragma unroll
            for (int i = 0; i < 4; ++i) {
                const int row = (2 * w + kt) * 16 + l4 * 4 + i;
                #pragma unroll
                for (int pt = 0; pt < 2; ++pt) {
                    float ev = e[kt][pt][i];
                    asr[kt][i] = fmaf(ev, rden[pt], asr[kt][i]);
                    ph[row * PH_S + pt * 16 + l15] = f2bf(ev * rdn2[pt]);
                }
            }
        // no barrier: mm2 reads only the ph rows this wave just wrote
        // (intra-wave LDS ordering is guaranteed).

        // ---- mm2: V[k][c] += P' @ Xraw^T (single-plane bf16) --------------
        {
            short8 xh2[4];
            #pragma unroll
            for (int ct = 0; ct < 4; ++ct)
                xh2[ct] = *(short8*)&xc[(ct * 16 + l15) * XC_S + l4 * 8];
            #pragma unroll
            for (int kt = 0; kt < 2; ++kt) {
                short8 ah = *(short8*)&ph[((2 * w + kt) * 16 + l15) * PH_S + l4 * 8];
                #pragma unroll
                for (int ct = 0; ct < 4; ++ct)
                    acc2[kt][ct] = MFMA(ah, xh2[ct], acc2[kt][ct]);
            }
        }
        __syncthreads();                                  // bar 3: chunk end
    }

    // ---- V write (coalesced: lanes l15 -> consecutive c) ------------------
    float* vg = use_atomic ? vout + (size_t)n * KCL * CDIM
                           : vout + (size_t)blockIdx.x * KCL * CDIM;
    #pragma unroll
    for (int kt = 0; kt < 2; ++kt)
        #pragma unroll
        for (int ct = 0; ct < 4; ++ct)
            #pragma unroll
            for (int i = 0; i < 4; ++i) {
                const int row = (2 * w + kt) * 16 + l4 * 4 + i;
                const int col = ct * 16 + l15;
                if (use_atomic) atomicAdd(&vg[row * CDIM + col], acc2[kt][ct][i]);
                else            vg[row * CDIM + col] = acc2[kt][ct][i];
            }

    // ---- asum: reduce over l15 lanes, lane0-of-16 writes ------------------
    #pragma unroll
    for (int kt = 0; kt < 2; ++kt)
        #pragma unroll
        for (int i = 0; i < 4; ++i) {
            float v = asr[kt][i];
            v += __shfl_xor(v, 1); v += __shfl_xor(v, 2);
            v += __shfl_xor(v, 4); v += __shfl_xor(v, 8);
            if (l15 == 0) {
                const int row = (2 * w + kt) * 16 + l4 * 4 + i;
                if (use_atomic) atomicAdd(&asout[n * KCL + row], v);
                else            asout[blockIdx.x * KCL + row] = v;
            }
        }
}

// ---------------------------------------------------------------------------
// Kernel 2: sum partials; vlad = V - asum*cent; intra-norm; global norm.
// After intra-norm every row has unit L2 norm -> global denom = sqrt(128).
// grid = NIMG*8 blocks x 256 threads; thread -> (k, 4 c's). Fully parallel.
// ---------------------------------------------------------------------------
__global__ __launch_bounds__(256)
void netvlad_finalize(const float* __restrict__ vpart,   // [N][nparts][K][C]
                      const float* __restrict__ aspart,  // [N][nparts][K]
                      const float* __restrict__ cent,    // [K][C]
                      float* __restrict__ out,           // [N][K*C]
                      int nparts)
{
    const int t = threadIdx.x;
    const int n  = blockIdx.x >> 3;
    const int kg = blockIdx.x & 7;
    const int k  = kg * 16 + (t >> 4);
    const int c0 = (t & 15) * 4;

    float vsum[4] = {0.f, 0.f, 0.f, 0.f};
    float av = 0.f;
    for (int pt = 0; pt < nparts; ++pt) {
        const float* vg = vpart + (((size_t)n * nparts + pt) * KCL + k) * CDIM + c0;
        float4 a = *(const float4*)vg;
        vsum[0] += a.x; vsum[1] += a.y; vsum[2] += a.z; vsum[3] += a.w;
        av += aspart[(n * nparts + pt) * KCL + k];
    }

    float4 cq = *(const float4*)(cent + k * CDIM + c0);
    float cc[4] = {cq.x, cq.y, cq.z, cq.w};
    float ss = 0.f;
    #pragma unroll
    for (int j = 0; j < 4; ++j) {
        vsum[j] -= av * cc[j];
        ss += vsum[j] * vsum[j];
    }
    // row sumsq over the 16 lanes covering this k
    ss += __shfl_xor(ss, 1); ss += __shfl_xor(ss, 2);
    ss += __shfl_xor(ss, 4); ss += __shfl_xor(ss, 8);
    const float s = (1.0f / fmaxf(sqrtf(ss), 1e-12f)) * RSQRT128;

    float4 o;
    o.x = vsum[0] * s; o.y = vsum[1] * s; o.z = vsum[2] * s; o.w = vsum[3] * s;
    *(float4*)(out + (size_t)n * KCL * CDIM + k * CDIM + c0) = o;
}

// ---------------------------------------------------------------------------
extern "C" void kernel_launch(void* const* d_in, const int* in_sizes, int n_in,
                              void* d_out, int out_size, void* d_ws, size_t ws_size,
                              hipStream_t stream) {
    const float* x     = (const float*)d_in[0];   // [64,64,64,64]
    const float* cent  = (const float*)d_in[1];   // [128,64]
    const float* convw = (const float*)d_in[2];   // [128,64]
    const float* convb = (const float*)d_in[3];   // [128]
    float* out = (float*)d_out;

    const size_t need8 = (size_t)NIMG * PARTS * (KCL * CDIM + KCL) * sizeof(float);

    if (ws_size >= need8) {
        float* vws  = (float*)d_ws;                               // [N][8][K][C]
        float* asws = vws + (size_t)NIMG * PARTS * KCL * CDIM;    // [N][8][K]
        netvlad_main<PARTS><<<dim3(NIMG * PARTS), dim3(256), 0, stream>>>(
            x, convw, convb, vws, asws, 0);
        netvlad_finalize<<<dim3(NIMG * 8), dim3(256), 0, stream>>>(
            vws, asws, cent, out, PARTS);
    } else {
        float* vws  = (float*)d_ws;                               // [N][K][C]
        float* asws = vws + (size_t)NIMG * KCL * CDIM;            // [N][K]
        const size_t zb = (size_t)NIMG * (KCL * CDIM + KCL) * sizeof(float);
        hipMemsetAsync(d_ws, 0, zb, stream);
        netvlad_main<PARTS><<<dim3(NIMG * PARTS), dim3(256), 0, stream>>>(
            x, convw, convb, vws, asws, 1);
        netvlad_finalize<<<dim3(NIMG * 8), dim3(256), 0, stream>>>(
            vws, asws, cent, out, 1);
    }
}